// Round 3
// baseline (178.951 us; speedup 1.0000x reference)
//
#include <hip/hip_runtime.h>

typedef __bf16 bf16x8 __attribute__((ext_vector_type(8)));
typedef float  f32x4  __attribute__((ext_vector_type(4)));

#define ND   64
#define HD   128
#define NSEG 1024
#define RPB  2048          // rows per block (32 tiles of 64)

__device__ __forceinline__ int lower_bound_i(const int* __restrict__ a, int n, int v) {
  int lo = 0, hi = n;
  while (lo < hi) { int m = (lo + hi) >> 1; if (a[m] < v) lo = m + 1; else hi = m; }
  return lo;
}

__global__ __launch_bounds__(128) void k_init(const int* __restrict__ xb, int n,
                                              float* __restrict__ sums,
                                              float* __restrict__ counts) {
  const int s = blockIdx.x;
  sums[s * HD + threadIdx.x] = 0.f;
  if (threadIdx.x == 0) {
    int lo = lower_bound_i(xb, n, s);
    int hi = lower_bound_i(xb, n, s + 1);
    counts[s] = (float)(hi - lo);
  }
}

__device__ __forceinline__ void flush_seg(float* __restrict__ sums, int seg,
                                          float* seg_acc, int lane) {
  #pragma unroll
  for (int ct = 0; ct < 8; ++ct) {
    float v = seg_acc[ct];
    v += __shfl_xor(v, 16);
    v += __shfl_xor(v, 32);
    if (lane < 16) atomicAdd(&sums[seg * HD + ct * 16 + lane], v);
  }
}

// K1: segment-sum of relu(x @ W1 + b1) into sums[1024][128].
// Per-wave private LDS streaming: 3 buffers x 4KB/wave, global_load_lds with
// inverse-XOR-swizzled source (linear dest), counted vmcnt(10) (never 0),
// NO barriers in the main loop (each wave stages only its own tiles).
// W1 fragments live in VGPRs (64 regs); 3 blocks/CU (48KB LDS), 3 waves/SIMD.
// A frag: lane=(l16 row, lgrp kgrp), k = kt*32 + lgrp*8 + e. B frag: same k map.
// D frag: col = lane&15, row = 4*(lane>>4)+reg  (HW-verified in R1/R2).
__global__ __launch_bounds__(256, 3) void k_phi(const float* __restrict__ x,
                                                const int* __restrict__ xb,
                                                const float* __restrict__ W1,
                                                const float* __restrict__ b1,
                                                float* __restrict__ sums, int n) {
  __shared__ __align__(16) char lds[48 * 1024];   // [wave][3 bufs][4096]
  const int lane = threadIdx.x & 63;
  const int wave = threadIdx.x >> 6;
  const int l16  = lane & 15;
  const int lgrp = lane >> 4;

  // ---- stage W1 frag-layout into LDS (coalesced-ish), then pull into VGPRs ----
  #pragma unroll
  for (int i = 0; i < 4; ++i) {
    const int f = wave + i * 4, kt = f >> 3, ct = f & 7;
    bf16x8 fr;
    #pragma unroll
    for (int e = 0; e < 8; ++e)
      fr[e] = (__bf16)W1[(kt * 32 + lgrp * 8 + e) * HD + ct * 16 + l16];
    *(bf16x8*)(&lds[f * 1024 + lane * 16]) = fr;
  }
  __syncthreads();
  bf16x8 bfrag[2][8];
  #pragma unroll
  for (int kt = 0; kt < 2; ++kt)
    #pragma unroll
    for (int ct = 0; ct < 8; ++ct)
      bfrag[kt][ct] = *(const bf16x8*)(&lds[(kt * 8 + ct) * 1024 + lane * 16]);
  float b1v[8];
  #pragma unroll
  for (int ct = 0; ct < 8; ++ct) b1v[ct] = b1[ct * 16 + l16];
  __syncthreads();   // all frag reads done before stream buffers overwrite this LDS

  const int row0 = blockIdx.x * RPB;
  if (row0 >= n) return;
  const int iters = min(RPB, n - row0) >> 6;   // n % 64 == 0

  // per-lane swizzled SOURCE offsets for the 4 global_load_lds issues per tile.
  // linear in-tile offset o = j*1024 + lane*16; row(o) = j*4 + lgrp;
  // src_off = o ^ ((row(o)&7)<<4)  (involution, bits 4-6 only)
  int soff[4];
  #pragma unroll
  for (int j = 0; j < 4; ++j)
    soff[j] = ((j << 10) + (lane << 4)) ^ (((lgrp + 4 * (j & 1)) & 7) << 4);

  // per-lane swizzled READ offsets (within a 4KB tile): logical l16*256 + lgrp*32 (+16/+128/+144)
  const int p0 = (l16 * 256 + lgrp * 32) ^ ((l16 & 7) << 4);
  const int p1 = p0 ^ 16;

  const char* xbase  = (const char*)x + (size_t)(row0 + wave * 16) * 256;
  const int*  xbbase = xb + row0 + wave * 16 + l16;
  char*       mylds  = &lds[wave * 12288];

#define STAGE(TT, BB)                                                              \
  {                                                                                \
    const char* _s = xbase + (size_t)(TT) * 16384;                                 \
    char*       _d = mylds + (BB) * 4096;                                          \
    _Pragma("unroll")                                                              \
    for (int j = 0; j < 4; ++j)                                                    \
      __builtin_amdgcn_global_load_lds(                                            \
          (const __attribute__((address_space(1))) void*)(_s + soff[j]),           \
          (__attribute__((address_space(3))) void*)(_d + j * 1024), 16, 0, 0);     \
  }

  float seg_acc[8] = {0.f, 0.f, 0.f, 0.f, 0.f, 0.f, 0.f, 0.f};
  int seg_cur = -1;

  // prologue: tiles 0,1 in flight (10 vmem ops: 2x(4 gload + 1 xb))
  STAGE(0, 0);
  int sbA = xbbase[0];
  STAGE(1, 1);
  int sbB = xbbase[64];

  int bcur = 0, bw = 2;   // consume buffer, write buffer ((t)%3, (t+2)%3)

  for (int t = 0; t < iters; ++t) {
    const int tn = (t + 2 < iters) ? (t + 2) : (iters - 1);  // clamped tail re-stage
    STAGE(tn, bw);
    int sbC = xbbase[tn * 64];
    // tile t's 5 vmem ops are the oldest 5 of <=15 outstanding -> drain them:
    asm volatile("s_waitcnt vmcnt(10)" ::: "memory");

    {
      int sfirst = __builtin_amdgcn_readfirstlane(sbA);
      const bool uni = (__all(sbA == sfirst) != 0);
      const char* bp = mylds + bcur * 4096;
      f32x4 v0 = *(const f32x4*)(bp + p0);
      f32x4 v1 = *(const f32x4*)(bp + p1);
      f32x4 v2 = *(const f32x4*)(bp + p0 + 128);
      f32x4 v3 = *(const f32x4*)(bp + p1 + 128);
      bf16x8 a0, a1;
      #pragma unroll
      for (int e = 0; e < 4; ++e) {
        a0[e] = (__bf16)v0[e]; a0[e + 4] = (__bf16)v1[e];
        a1[e] = (__bf16)v2[e]; a1[e + 4] = (__bf16)v3[e];
      }
      f32x4 acc[8];
      #pragma unroll
      for (int ct = 0; ct < 8; ++ct) {
        f32x4 c; c[0] = c[1] = c[2] = c[3] = b1v[ct];
        c = __builtin_amdgcn_mfma_f32_16x16x32_bf16(a0, bfrag[0][ct], c, 0, 0, 0);
        acc[ct] = __builtin_amdgcn_mfma_f32_16x16x32_bf16(a1, bfrag[1][ct], acc[ct] = c, 0, 0, 0);
      }
      if (uni) {
        if (sfirst != seg_cur) {
          if (seg_cur >= 0) flush_seg(sums, seg_cur, seg_acc, lane);
          #pragma unroll
          for (int ct = 0; ct < 8; ++ct) seg_acc[ct] = 0.f;
          seg_cur = sfirst;
        }
        #pragma unroll
        for (int ct = 0; ct < 8; ++ct)
          seg_acc[ct] += (fmaxf(acc[ct][0], 0.f) + fmaxf(acc[ct][1], 0.f)) +
                         (fmaxf(acc[ct][2], 0.f) + fmaxf(acc[ct][3], 0.f));
      } else {
        if (seg_cur >= 0) flush_seg(sums, seg_cur, seg_acc, lane);
        #pragma unroll
        for (int ct = 0; ct < 8; ++ct) seg_acc[ct] = 0.f;
        const int* xq = xb + row0 + t * 64 + wave * 16 + lgrp * 4;
        const int s0 = xq[0], s1 = xq[1], s2 = xq[2], s3 = xq[3];
        #pragma unroll
        for (int ct = 0; ct < 8; ++ct) {
          atomicAdd(&sums[s0 * HD + ct * 16 + l16], fmaxf(acc[ct][0], 0.f));
          atomicAdd(&sums[s1 * HD + ct * 16 + l16], fmaxf(acc[ct][1], 0.f));
          atomicAdd(&sums[s2 * HD + ct * 16 + l16], fmaxf(acc[ct][2], 0.f));
          atomicAdd(&sums[s3 * HD + ct * 16 + l16], fmaxf(acc[ct][3], 0.f));
        }
        seg_cur = __shfl(sbA, 15);
      }
    }

    sbA = sbB; sbB = sbC;
    bcur = (bcur == 2) ? 0 : bcur + 1;
    bw   = (bw   == 2) ? 0 : bw   + 1;
  }
#undef STAGE

  if (seg_cur >= 0) flush_seg(sums, seg_cur, seg_acc, lane);
}

// K2: per segment: mean -> @W2+b2 (deferred past the mean) -> relu(@W3+b3) -> @W4+b4
__global__ __launch_bounds__(128) void k_rho(const float* __restrict__ sums,
                                             const float* __restrict__ counts,
                                             const float* __restrict__ W2, const float* __restrict__ b2,
                                             const float* __restrict__ W3, const float* __restrict__ b3,
                                             const float* __restrict__ W4, const float* __restrict__ b4,
                                             float* __restrict__ out) {
  const int s = blockIdx.x;
  const int j = threadIdx.x;
  __shared__ float bufA[HD];
  __shared__ float bufB[HD];

  const float c = counts[s];
  const float inv = 1.f / fmaxf(c, 1.f);
  bufA[j] = sums[s * HD + j] * inv;
  __syncthreads();

  float hid = b2[j];
  #pragma unroll 4
  for (int k = 0; k < HD; ++k) hid = fmaf(bufA[k], W2[k * HD + j], hid);
  if (c == 0.f) hid = 0.f;
  bufB[j] = hid;
  __syncthreads();

  float t = b3[j];
  #pragma unroll 4
  for (int k = 0; k < HD; ++k) t = fmaf(bufB[k], W3[k * HD + j], t);
  t = fmaxf(t, 0.f);
  bufA[j] = t;
  __syncthreads();

  if (j < 16) {
    float o = b4[j];
    #pragma unroll 4
    for (int k = 0; k < HD; ++k) o = fmaf(bufA[k], W4[k * 16 + j], o);
    out[s * 16 + j] = o;
  }
}

extern "C" void kernel_launch(void* const* d_in, const int* in_sizes, int n_in,
                              void* d_out, int out_size, void* d_ws, size_t ws_size,
                              hipStream_t stream) {
  const float* x  = (const float*)d_in[0];
  const int*   xb = (const int*)  d_in[1];
  const float* W1 = (const float*)d_in[2];
  const float* b1 = (const float*)d_in[3];
  const float* W2 = (const float*)d_in[4];
  const float* b2 = (const float*)d_in[5];
  const float* W3 = (const float*)d_in[6];
  const float* b3 = (const float*)d_in[7];
  const float* W4 = (const float*)d_in[8];
  const float* b4 = (const float*)d_in[9];
  float* out = (float*)d_out;
  const int n = in_sizes[1];

  float* sums   = (float*)d_ws;              // [NSEG][HD]
  float* counts = sums + (size_t)NSEG * HD;  // [NSEG]

  k_init<<<NSEG, 128, 0, stream>>>(xb, n, sums, counts);
  const int nblocks = (n + RPB - 1) / RPB;
  k_phi<<<nblocks, 256, 0, stream>>>(x, xb, W1, b1, sums, n);
  k_rho<<<NSEG, 128, 0, stream>>>(sums, counts, W2, b2, W3, b3, W4, b4, out);
}

// Round 4
// 168.677 us; speedup vs baseline: 1.0609x; 1.0609x over previous
//
#include <hip/hip_runtime.h>

typedef __bf16 bf16x8 __attribute__((ext_vector_type(8)));
typedef float  f32x4  __attribute__((ext_vector_type(4)));

#define ND   64
#define HD   128
#define NSEG 1024
#define RPB  1024          // rows per block (16 tiles of 64)

__device__ __forceinline__ int lower_bound_i(const int* __restrict__ a, int n, int v) {
  int lo = 0, hi = n;
  while (lo < hi) { int m = (lo + hi) >> 1; if (a[m] < v) lo = m + 1; else hi = m; }
  return lo;
}

__global__ __launch_bounds__(128) void k_init(const int* __restrict__ xb, int n,
                                              float* __restrict__ sums,
                                              float* __restrict__ counts) {
  const int s = blockIdx.x;
  sums[s * HD + threadIdx.x] = 0.f;
  if (threadIdx.x == 0) {
    int lo = lower_bound_i(xb, n, s);
    int hi = lower_bound_i(xb, n, s + 1);
    counts[s] = (float)(hi - lo);
  }
}

__device__ __forceinline__ void flush_seg(float* __restrict__ sums, int seg,
                                          float* seg_acc, int lane) {
  #pragma unroll
  for (int ct = 0; ct < 8; ++ct) {
    float v = seg_acc[ct];
    v += __shfl_xor(v, 16);
    v += __shfl_xor(v, 32);
    if (lane < 16) atomicAdd(&sums[seg * HD + ct * 16 + lane], v);
  }
}

// K1: segment-sum of relu(x @ W1 + b1) into sums[1024][128].
// All-register kernel: W1 frags in VGPRs (64), NO LDS, NO barriers.
// launch_bounds(256,2): 256-VGPR budget so regalloc cannot collapse the
// depth-2 software pipeline (three named tile slots A/B/C; every load's
// consumer is 2 iterations downstream; compiler emits counted vmcnt).
// A frag: lane=(l16 row, lgrp kgrp), k = kt*32 + lgrp*8 + e. B frag: same k map
// (same map on both operands => correct for any true hardware k-order).
// D frag: col = lane&15, row = 4*(lane>>4)+reg  (HW-verified R1-R3).
__global__ __launch_bounds__(256, 2) void k_phi(const float* __restrict__ x,
                                                const int* __restrict__ xb,
                                                const float* __restrict__ W1,
                                                const float* __restrict__ b1,
                                                float* __restrict__ sums, int n) {
  const int lane = threadIdx.x & 63;
  const int wave = threadIdx.x >> 6;
  const int l16  = lane & 15;
  const int lgrp = lane >> 4;

  // W1 fragments gathered straight into VGPRs (W1 is 32KB, L2-hot)
  bf16x8 bfrag[2][8];
  #pragma unroll
  for (int kt = 0; kt < 2; ++kt)
    #pragma unroll
    for (int ct = 0; ct < 8; ++ct) {
      bf16x8 f;
      #pragma unroll
      for (int e = 0; e < 8; ++e)
        f[e] = (__bf16)W1[(kt * 32 + lgrp * 8 + e) * HD + ct * 16 + l16];
      bfrag[kt][ct] = f;
    }
  float b1v[8];
  #pragma unroll
  for (int ct = 0; ct < 8; ++ct) b1v[ct] = b1[ct * 16 + l16];

  const int row0 = blockIdx.x * RPB;
  if (row0 >= n) return;
  const int iters = min(RPB, n - row0) >> 6;   // n % 64 == 0

  const float* xp  = x + (size_t)(row0 + wave * 16 + l16) * ND + lgrp * 8;
  const int*   xbp = xb + row0 + wave * 16 + l16;

  float seg_acc[8] = {0.f, 0.f, 0.f, 0.f, 0.f, 0.f, 0.f, 0.f};
  int   seg_cur = -1;

  // three tile slots, depth-2 pipeline
  f32x4 A0, A1, A2, A3, B0, B1, B2, B3, C0, C1, C2, C3;
  int sbA, sbB, sbC;

#define LOADT(T, R0, R1, R2, R3, SB)                         \
  {                                                          \
    const float* _p = xp + (size_t)(T) * (64 * ND);          \
    R0 = *(const f32x4*)(_p);                                \
    R1 = *(const f32x4*)(_p + 4);                            \
    R2 = *(const f32x4*)(_p + 32);                           \
    R3 = *(const f32x4*)(_p + 36);                           \
    SB = xbp[(T) * 64];                                      \
  }

  LOADT(0, A0, A1, A2, A3, sbA);
  {
    const int t1 = (iters > 1) ? 1 : 0;
    LOADT(t1, B0, B1, B2, B3, sbB);
  }

  for (int t = 0; t < iters; ++t) {
    const int tn = (t + 2 < iters) ? (t + 2) : (iters - 1);
    LOADT(tn, C0, C1, C2, C3, sbC);

    {
      int sfirst = __builtin_amdgcn_readfirstlane(sbA);
      const bool uni = (__all(sbA == sfirst) != 0);
      bf16x8 a0, a1;
      #pragma unroll
      for (int e = 0; e < 4; ++e) {
        a0[e] = (__bf16)A0[e]; a0[e + 4] = (__bf16)A1[e];
        a1[e] = (__bf16)A2[e]; a1[e + 4] = (__bf16)A3[e];
      }
      f32x4 acc[8];
      #pragma unroll
      for (int ct = 0; ct < 8; ++ct) {
        f32x4 c; c[0] = c[1] = c[2] = c[3] = b1v[ct];
        c = __builtin_amdgcn_mfma_f32_16x16x32_bf16(a0, bfrag[0][ct], c, 0, 0, 0);
        c = __builtin_amdgcn_mfma_f32_16x16x32_bf16(a1, bfrag[1][ct], c, 0, 0, 0);
        acc[ct] = c;
      }
      if (uni) {
        if (sfirst != seg_cur) {
          if (seg_cur >= 0) flush_seg(sums, seg_cur, seg_acc, lane);
          #pragma unroll
          for (int ct = 0; ct < 8; ++ct) seg_acc[ct] = 0.f;
          seg_cur = sfirst;
        }
        #pragma unroll
        for (int ct = 0; ct < 8; ++ct)
          seg_acc[ct] += (fmaxf(acc[ct][0], 0.f) + fmaxf(acc[ct][1], 0.f)) +
                         (fmaxf(acc[ct][2], 0.f) + fmaxf(acc[ct][3], 0.f));
      } else {
        if (seg_cur >= 0) flush_seg(sums, seg_cur, seg_acc, lane);
        #pragma unroll
        for (int ct = 0; ct < 8; ++ct) seg_acc[ct] = 0.f;
        const int* xq = xb + row0 + t * 64 + wave * 16 + lgrp * 4;
        const int s0 = xq[0], s1 = xq[1], s2 = xq[2], s3 = xq[3];
        #pragma unroll
        for (int ct = 0; ct < 8; ++ct) {
          atomicAdd(&sums[s0 * HD + ct * 16 + l16], fmaxf(acc[ct][0], 0.f));
          atomicAdd(&sums[s1 * HD + ct * 16 + l16], fmaxf(acc[ct][1], 0.f));
          atomicAdd(&sums[s2 * HD + ct * 16 + l16], fmaxf(acc[ct][2], 0.f));
          atomicAdd(&sums[s3 * HD + ct * 16 + l16], fmaxf(acc[ct][3], 0.f));
        }
        seg_cur = __shfl(sbA, 15);
      }
    }

    // rotate slots (register copies; cheap vs 3000-cy tile period)
    A0 = B0; A1 = B1; A2 = B2; A3 = B3; sbA = sbB;
    B0 = C0; B1 = C1; B2 = C2; B3 = C3; sbB = sbC;
  }
#undef LOADT

  if (seg_cur >= 0) flush_seg(sums, seg_cur, seg_acc, lane);
}

// K2: per segment: mean -> @W2+b2 (deferred past the mean) -> relu(@W3+b3) -> @W4+b4
__global__ __launch_bounds__(128) void k_rho(const float* __restrict__ sums,
                                             const float* __restrict__ counts,
                                             const float* __restrict__ W2, const float* __restrict__ b2,
                                             const float* __restrict__ W3, const float* __restrict__ b3,
                                             const float* __restrict__ W4, const float* __restrict__ b4,
                                             float* __restrict__ out) {
  const int s = blockIdx.x;
  const int j = threadIdx.x;
  __shared__ float bufA[HD];
  __shared__ float bufB[HD];

  const float c = counts[s];
  const float inv = 1.f / fmaxf(c, 1.f);
  bufA[j] = sums[s * HD + j] * inv;
  __syncthreads();

  float hid = b2[j];
  #pragma unroll 4
  for (int k = 0; k < HD; ++k) hid = fmaf(bufA[k], W2[k * HD + j], hid);
  if (c == 0.f) hid = 0.f;
  bufB[j] = hid;
  __syncthreads();

  float t = b3[j];
  #pragma unroll 4
  for (int k = 0; k < HD; ++k) t = fmaf(bufB[k], W3[k * HD + j], t);
  t = fmaxf(t, 0.f);
  bufA[j] = t;
  __syncthreads();

  if (j < 16) {
    float o = b4[j];
    #pragma unroll 4
    for (int k = 0; k < HD; ++k) o = fmaf(bufA[k], W4[k * 16 + j], o);
    out[s * 16 + j] = o;
  }
}

extern "C" void kernel_launch(void* const* d_in, const int* in_sizes, int n_in,
                              void* d_out, int out_size, void* d_ws, size_t ws_size,
                              hipStream_t stream) {
  const float* x  = (const float*)d_in[0];
  const int*   xb = (const int*)  d_in[1];
  const float* W1 = (const float*)d_in[2];
  const float* b1 = (const float*)d_in[3];
  const float* W2 = (const float*)d_in[4];
  const float* b2 = (const float*)d_in[5];
  const float* W3 = (const float*)d_in[6];
  const float* b3 = (const float*)d_in[7];
  const float* W4 = (const float*)d_in[8];
  const float* b4 = (const float*)d_in[9];
  float* out = (float*)d_out;
  const int n = in_sizes[1];

  float* sums   = (float*)d_ws;              // [NSEG][HD]
  float* counts = sums + (size_t)NSEG * HD;  // [NSEG]

  k_init<<<NSEG, 128, 0, stream>>>(xb, n, sums, counts);
  const int nblocks = (n + RPB - 1) / RPB;
  k_phi<<<nblocks, 256, 0, stream>>>(x, xb, W1, b1, sums, n);
  k_rho<<<NSEG, 128, 0, stream>>>(sums, counts, W2, b2, W3, b3, W4, b4, out);
}